// Round 11
// baseline (71.664 us; speedup 1.0000x reference)
//
#include <hip/hip_runtime.h>
#include <stdint.h>

// GCLSTM (single step, H=C=0) + MLP head, bf16 MFMA, fp32 accum/activations.
// Transposed formulation: G^T = W^T @ X^T, C-frags hold (col=node, row=feat).
// R11 changes vs R10 (issue-bound: cut trans ops, keep R5's best launch config):
//  - tanh(a_c) and tanh(c) via Pade[5/4] x(945+105y+y^2)/(945+420y+15y^2):
//    both inputs bounded (|a_c|<~1.4, |c|<0.9) => err <1e-5, no clamps needed.
//  - sigmoids keep exp2 (range-unbounded, exp is correct tool); Pade
//    denominators FOLDED into the existing 4-wide batched rcp:
//    c = ac*nn / [dd*(1+Ei)], h = c*nn2 / [dd2*(1+Eo)]  -> 2 exp2 + 0.5 rcp/elem
//    (was 4 exp2 + 0.5 rcp): ~86 cyc/elem vs 104 measured-model.
//  - launch_bounds(512,6): VGPR cap 85 (R6's Pade spill was the (512,8)=64 cap).
//  - grid/iter = R5's best config (1954 blocks, 2 tiles/wave).

typedef __attribute__((ext_vector_type(8))) short bf16x8;   // 8 bf16 = 4 VGPR
typedef __attribute__((ext_vector_type(4))) float f32x4;

constexpr int IN_F = 16;
constexpr int HID  = 128;
constexpr int MH1  = 64;
constexpr int MH2  = 32;
constexpr int WAVES = 8;
constexpr int ITER  = 2;                        // tiles per wave per block
constexpr int TILES_PER_BLOCK = WAVES * ITER;   // 16

constexpr float LOG2E = 1.4426950408889634f;

// ---- LDS byte offsets ----
constexpr int GATE_F = 0;                   // 24 tiles * 512 B (lanes 0..31 real)
constexpr int M1_F   = 12288;               // 16 tiles * 1024 B
constexpr int M2_F   = 28672;               // 4 tiles * 1024 B
constexpr int BIAS_O = 32768;               // 3*128 f32 (scaled, hid-permuted)
constexpr int WCO_O  = 34304;               // 128 f32 (-L*w_co, hid-permuted)
constexpr int M3_O   = 34816;               // 32 f32
constexpr int BM1_O  = 34944;               // 64 f32 (m1-permuted)
constexpr int BM2_O  = 35200;               // 32 f32
constexpr int BM3_O  = 35328;               // 1 f32
constexpr int LDS_BYTES = 35392;

__device__ __forceinline__ short f2bf(float f) {   // RNE float->bf16 (init only)
    uint32_t u = __builtin_bit_cast(uint32_t, f);
    u += 0x7fffu + ((u >> 16) & 1u);
    return (short)(u >> 16);
}
__device__ __forceinline__ uint32_t cvt_pk(float lo, float hi) {  // bf16(lo)|bf16(hi)<<16
    uint32_t r;
    asm("v_cvt_pk_bf16_f32 %0, %1, %2" : "=v"(r) : "v"(lo), "v"(hi));
    return r;
}
// row permutation: tile mt (0..T-1), row r (0..15) -> feature index
__device__ __forceinline__ int permrow(int mt, int r) {
    return ((mt >> 1) << 5) + ((r >> 2) << 3) + ((mt & 1) << 2) + (r & 3);
}

__global__ __launch_bounds__(512, 6) void gclstm_mfma_kernel(
    const float* __restrict__ x,
    const float* __restrict__ W_i, const float* __restrict__ W_c, const float* __restrict__ W_o,
    const float* __restrict__ bc_i, const float* __restrict__ bc_c, const float* __restrict__ bc_o,
    const float* __restrict__ w_co,
    const float* __restrict__ b_i, const float* __restrict__ b_c, const float* __restrict__ b_o,
    const float* __restrict__ M1, const float* __restrict__ bm1,
    const float* __restrict__ M2, const float* __restrict__ bm2,
    const float* __restrict__ M3, const float* __restrict__ bm3,
    float* __restrict__ out, int n)
{
    __shared__ __align__(16) char lds[LDS_BYTES];
    const int tid  = threadIdx.x;
    const int wid  = tid >> 6;
    const int lane = tid & 63;
    const int g    = lane >> 4;     // lane group 0..3
    const int ln   = lane & 15;

    // ---------------- init: build scaled, row-permuted bf16 fragment tables ----
    if (lane < 32) {
        for (int t = wid; t < 24; t += WAVES) {
            const int gi = t >> 3, mt = t & 7;
            const float* Wg = (gi == 0) ? W_i : (gi == 1) ? W_c : W_o;
            const float sc  = (gi == 1) ? 1.0f : -LOG2E;   // c-gate natural (Pade)
            const int row = permrow(mt, ln);  // permuted hid index
            const int k0  = g * 8;            // input-feature index (g in 0..1)
            bf16x8 v;
            #pragma unroll
            for (int j = 0; j < 8; ++j) v[j] = f2bf(Wg[(k0 + j) * HID + row] * sc);
            *(bf16x8*)(lds + GATE_F + t * 512 + lane * 16) = v;
        }
    }
    // M1^T frags: A[r][k] = M1[k*64 + permrow(mt1, r)]; K(hid) natural order.
    for (int t = wid; t < 16; t += WAVES) {
        const int mt = t >> 2, kt = t & 3;
        const int row = permrow(mt, ln);      // permuted m1 index (mt in 0..3)
        const int k0  = kt * 32 + g * 8;
        bf16x8 v;
        #pragma unroll
        for (int j = 0; j < 8; ++j) v[j] = f2bf(M1[(k0 + j) * MH1 + row]);
        *(bf16x8*)(lds + M1_F + t * 1024 + lane * 16) = v;
    }
    // M2^T frags: A[r][k] = M2[k*32 + (mt2*16+r)]; K(m1) natural; rows natural.
    for (int t = wid; t < 4; t += WAVES) {
        const int mt = t >> 1, kt = t & 1;
        const int row = mt * 16 + ln;
        const int k0  = kt * 32 + g * 8;
        bf16x8 v;
        #pragma unroll
        for (int j = 0; j < 8; ++j) v[j] = f2bf(M2[(k0 + j) * MH2 + row]);
        *(bf16x8*)(lds + M2_F + t * 1024 + lane * 16) = v;
    }
    {
        float* biasS = (float*)(lds + BIAS_O);
        if (tid < HID) {
            const int h = permrow(tid >> 4, tid & 15);    // hid perm, mt in 0..7
            biasS[tid]           = (bc_i[h] + b_i[h]) * (-LOG2E);
            biasS[HID + tid]     = (bc_c[h] + b_c[h]);            // natural
            biasS[2 * HID + tid] = (bc_o[h] + b_o[h]) * (-LOG2E);
            ((float*)(lds + WCO_O))[tid] = -LOG2E * w_co[h];
        }
        if (tid < MH1) {
            const int m = permrow(tid >> 4, tid & 15);    // m1 perm, mt in 0..3
            ((float*)(lds + BM1_O))[tid] = bm1[m];
        }
        if (tid < MH2) { ((float*)(lds + M3_O))[tid]  = M3[tid];
                         ((float*)(lds + BM2_O))[tid] = bm2[tid]; }
        if (tid == 0)  ((float*)(lds + BM3_O))[0] = bm3[0];
    }
    __syncthreads();

    const float* biasI = (const float*)(lds + BIAS_O);
    const float* biasC = biasI + HID;
    const float* biasO = biasC + HID;
    const float* wcoS  = (const float*)(lds + WCO_O);
    const float* m3S   = (const float*)(lds + M3_O);
    const float* bm1S  = (const float*)(lds + BM1_O);
    const float* bm2S  = (const float*)(lds + BM2_O);
    const float  bm3v  = ((const float*)(lds + BM3_O))[0];

    for (int it = 0; it < ITER; ++it) {
        const long tileIdx = (long)blockIdx.x * TILES_PER_BLOCK + it * WAVES + wid;
        const long base = tileIdx * 16;
        if (base >= n) break;

        // x B-frag: lane holds col=node(ln), k=g*8+j; k>=16 -> 0.
        bf16x8 xf;
        #pragma unroll
        for (int j = 0; j < 8; ++j) xf[j] = 0;
        if (g < 2) {
            const float* xp = x + (base + ln) * IN_F + g * 8;
            float4 a = *(const float4*)xp;
            float4 b = *(const float4*)(xp + 4);
            union { uint32_t u[4]; bf16x8 v; } cv;
            cv.u[0] = cvt_pk(a.x, a.y); cv.u[1] = cvt_pk(a.z, a.w);
            cv.u[2] = cvt_pk(b.x, b.y); cv.u[3] = cvt_pk(b.z, b.w);
            xf = cv.v;
        }

        // ---- gates + activations; hpk holds packed H (permuted rows -> B-frags).
        uint32_t hpk[16];
        #pragma unroll
        for (int mt = 0; mt < 8; ++mt) {
            const int h0 = mt * 16 + g * 4;             // permuted-bias position
            bf16x8 fi = *(const bf16x8*)(lds + GATE_F + (0 * 8 + mt) * 512 + (lane & 31) * 16);
            bf16x8 fc = *(const bf16x8*)(lds + GATE_F + (1 * 8 + mt) * 512 + (lane & 31) * 16);
            bf16x8 fo = *(const bf16x8*)(lds + GATE_F + (2 * 8 + mt) * 512 + (lane & 31) * 16);
            f32x4 bI = *(const f32x4*)(biasI + h0);
            f32x4 bC = *(const f32x4*)(biasC + h0);
            f32x4 bO = *(const f32x4*)(biasO + h0);
            // ai = -L*a_i ; ac = a_c (natural) ; ao = -L*(x@W_o+b_o)
            f32x4 ai = __builtin_amdgcn_mfma_f32_16x16x32_bf16(fi, xf, bI, 0, 0, 0);
            f32x4 ac = __builtin_amdgcn_mfma_f32_16x16x32_bf16(fc, xf, bC, 0, 0, 0);
            f32x4 ao = __builtin_amdgcn_mfma_f32_16x16x32_bf16(fo, xf, bO, 0, 0, 0);
            f32x4 wc = *(const f32x4*)(wcoS + h0);      // -L*w_co

            // Stage A: c = sigma(a_i)*tanh(a_c) = ac*nn / [dd*(1+Ei)]
            // (tanh via Pade[5/4], |a_c| <~1.4 => err <1e-6; one batched rcp)
            float numA[4], denA[4];
            #pragma unroll
            for (int i = 0; i < 4; ++i) {
                float Ei = __builtin_amdgcn_exp2f(ai[i]);   // e^{-a_i}
                float y  = ac[i] * ac[i];
                float nn = fmaf(y, y + 105.0f, 945.0f);
                float dd = fmaf(y, fmaf(y, 15.0f, 420.0f), 945.0f);
                numA[i] = ac[i] * nn;
                denA[i] = fmaf(dd, Ei, dd);                 // dd*(1+Ei)
            }
            float P01 = denA[0] * denA[1], P23 = denA[2] * denA[3];
            float R   = __builtin_amdgcn_rcpf(P01 * P23);
            float t01 = R * P23, t23 = R * P01;
            float cv0 = numA[0] * (t01 * denA[1]);
            float cv1 = numA[1] * (t01 * denA[0]);
            float cv2 = numA[2] * (t23 * denA[3]);
            float cv3 = numA[3] * (t23 * denA[2]);
            float cvx[4] = {cv0, cv1, cv2, cv3};

            // Stage B: h = sigma(a_o + w_co c)*tanh(c) = c*nn2 / [dd2*(1+Eo)]
            // (|c| < 0.9 => Pade err <1e-7; one batched rcp)
            float numB[4], denB[4];
            #pragma unroll
            for (int i = 0; i < 4; ++i) {
                float w  = fmaf(wc[i], cvx[i], ao[i]);      // -L*(a_o + w_co*c)
                float Eo = __builtin_amdgcn_exp2f(w);       // e^{-a_o'}
                float y  = cvx[i] * cvx[i];
                float nn = fmaf(y, y + 105.0f, 945.0f);
                float dd = fmaf(y, fmaf(y, 15.0f, 420.0f), 945.0f);
                numB[i] = cvx[i] * nn;
                denB[i] = fmaf(dd, Eo, dd);                 // dd2*(1+Eo)
            }
            float Q01 = denB[0] * denB[1], Q23 = denB[2] * denB[3];
            float R2  = __builtin_amdgcn_rcpf(Q01 * Q23);
            float s01 = R2 * Q23, s23 = R2 * Q01;
            float hv0 = fmaxf(numB[0] * (s01 * denB[1]), 0.0f);
            float hv1 = fmaxf(numB[1] * (s01 * denB[0]), 0.0f);
            float hv2 = fmaxf(numB[2] * (s23 * denB[3]), 0.0f);
            float hv3 = fmaxf(numB[3] * (s23 * denB[2]), 0.0f);

            hpk[mt * 2]     = cvt_pk(hv0, hv1);
            hpk[mt * 2 + 1] = cvt_pk(hv2, hv3);
        }

        // ---- MLP1: m1^T = M1^T @ H^T ; B-frag(kt) = hpk[4kt..4kt+3] ----
        uint32_t mpk[8];
        #pragma unroll
        for (int mt = 0; mt < 4; ++mt) {
            const int r0 = mt * 16 + g * 4;             // permuted-bias position
            f32x4 acc = *(const f32x4*)(bm1S + r0);     // bias as C-init
            #pragma unroll
            for (int kt = 0; kt < 4; ++kt) {
                union { uint32_t u[4]; bf16x8 v; } b;
                b.u[0] = hpk[4 * kt + 0]; b.u[1] = hpk[4 * kt + 1];
                b.u[2] = hpk[4 * kt + 2]; b.u[3] = hpk[4 * kt + 3];
                acc = __builtin_amdgcn_mfma_f32_16x16x32_bf16(
                    *(const bf16x8*)(lds + M1_F + (mt * 4 + kt) * 1024 + lane * 16), b.v, acc, 0, 0, 0);
            }
            float mv[4];
            #pragma unroll
            for (int i = 0; i < 4; ++i) mv[i] = fmaxf(acc[i], 0.f);
            mpk[mt * 2]     = cvt_pk(mv[0], mv[1]);
            mpk[mt * 2 + 1] = cvt_pk(mv[2], mv[3]);
        }

        // ---- MLP2 [32x64] + MLP3 dot; B-frag(kt2) = mpk[4kt2..4kt2+3] ----
        float outacc = 0.f;
        #pragma unroll
        for (int mt = 0; mt < 2; ++mt) {
            const int r0 = mt * 16 + g * 4;             // m2 index (natural)
            f32x4 acc = *(const f32x4*)(bm2S + r0);     // bias as C-init
            #pragma unroll
            for (int kt = 0; kt < 2; ++kt) {
                union { uint32_t u[4]; bf16x8 v; } b;
                b.u[0] = mpk[4 * kt + 0]; b.u[1] = mpk[4 * kt + 1];
                b.u[2] = mpk[4 * kt + 2]; b.u[3] = mpk[4 * kt + 3];
                acc = __builtin_amdgcn_mfma_f32_16x16x32_bf16(
                    *(const bf16x8*)(lds + M2_F + (mt * 2 + kt) * 1024 + lane * 16), b.v, acc, 0, 0, 0);
            }
            f32x4 w3 = *(const f32x4*)(m3S + r0);
            #pragma unroll
            for (int i = 0; i < 4; ++i)
                outacc = fmaf(fmaxf(acc[i], 0.f), w3[i], outacc);
        }
        outacc += __shfl_xor(outacc, 16);
        outacc += __shfl_xor(outacc, 32);
        if (lane < 16) out[base + lane] = outacc + bm3v;
    }
}

extern "C" void kernel_launch(void* const* d_in, const int* in_sizes, int n_in,
                              void* d_out, int out_size, void* d_ws, size_t ws_size,
                              hipStream_t stream) {
    const float* x    = (const float*)d_in[0];
    // d_in[1] edge_index, d_in[2] edge_weight: dead (ChebConv K=1 on H=0)
    const float* W_i  = (const float*)d_in[3];
    // d_in[4] W_f: dead (multiplies C=0)
    const float* W_c  = (const float*)d_in[5];
    const float* W_o  = (const float*)d_in[6];
    // d_in[7..10] Uc_*: dead (H=0)
    const float* bc_i = (const float*)d_in[11];
    const float* bc_c = (const float*)d_in[13];
    const float* bc_o = (const float*)d_in[14];
    const float* w_co = (const float*)d_in[17];
    const float* b_i  = (const float*)d_in[18];
    const float* b_c  = (const float*)d_in[20];
    const float* b_o  = (const float*)d_in[21];
    const float* M1   = (const float*)d_in[22];
    const float* bm1  = (const float*)d_in[23];
    const float* M2   = (const float*)d_in[24];
    const float* bm2  = (const float*)d_in[25];
    const float* M3   = (const float*)d_in[26];
    const float* bm3  = (const float*)d_in[27];
    float* out = (float*)d_out;

    const int n = in_sizes[0] / IN_F;                   // 500000
    const int tiles = (n + 15) / 16;                    // 31250
    const int grid = (tiles + TILES_PER_BLOCK - 1) / TILES_PER_BLOCK;  // 1954

    gclstm_mfma_kernel<<<grid, 512, 0, stream>>>(
        x, W_i, W_c, W_o, bc_i, bc_c, bc_o, w_co,
        b_i, b_c, b_o, M1, bm1, M2, bm2, M3, bm3, out, n);
}

// Round 12
// 62.284 us; speedup vs baseline: 1.1506x; 1.1506x over previous
//
#include <hip/hip_runtime.h>
#include <stdint.h>

// GCLSTM (single step, H=C=0) + MLP head, bf16 MFMA, fp32 accum/activations.
// Transposed formulation: G^T = W^T @ X^T, C-frags hold (col=node, row=feat).
// R12 changes vs R5 (new bottleneck model: ds_read_b128 throughput ~83% of wall;
// trans ops are cheap — R5..R11 showed dur ANTIcorrelates with VALU op count):
//  - DUAL-TILE per wave: 2 node-tiles (32 nodes) share every LDS read.
//    Weight frags AND bias C-operands are tile-independent: read once per mt,
//    used by both tiles' MFMAs. LDS: 84 -> 42 ds_read_b128 per tile.
//  - Activation math = R5's exact path (exp2 x4 + rcp x2 per elem), known 62us
//    / absmax 3.05e-5 — isolates the LDS-sharing variable.
//  - launch_bounds(512,4): 128 VGPR cap fits ~100-reg peak, no spill risk.

typedef __attribute__((ext_vector_type(8))) short bf16x8;   // 8 bf16 = 4 VGPR
typedef __attribute__((ext_vector_type(4))) float f32x4;

constexpr int IN_F = 16;
constexpr int HID  = 128;
constexpr int MH1  = 64;
constexpr int MH2  = 32;
constexpr int WAVES = 8;
constexpr int TILES_PER_BLOCK = WAVES * 2;      // 2 tiles per wave

constexpr float LOG2E = 1.4426950408889634f;
constexpr float TWO_L = 2.8853900817779268f;

// ---- LDS byte offsets ----
constexpr int GATE_F = 0;                   // 24 tiles * 512 B (lanes 0..31 real)
constexpr int M1_F   = 12288;               // 16 tiles * 1024 B
constexpr int M2_F   = 28672;               // 4 tiles * 1024 B
constexpr int BIAS_O = 32768;               // 3*128 f32 (scaled, hid-permuted)
constexpr int WCO_O  = 34304;               // 128 f32 (-w_co/2, hid-permuted)
constexpr int M3_O   = 34816;               // 32 f32
constexpr int BM1_O  = 34944;               // 64 f32 (m1-permuted)
constexpr int BM2_O  = 35200;               // 32 f32
constexpr int BM3_O  = 35328;               // 1 f32
constexpr int LDS_BYTES = 35392;

__device__ __forceinline__ short f2bf(float f) {   // RNE float->bf16 (init only)
    uint32_t u = __builtin_bit_cast(uint32_t, f);
    u += 0x7fffu + ((u >> 16) & 1u);
    return (short)(u >> 16);
}
__device__ __forceinline__ uint32_t cvt_pk(float lo, float hi) {  // bf16(lo)|bf16(hi)<<16
    uint32_t r;
    asm("v_cvt_pk_bf16_f32 %0, %1, %2" : "=v"(r) : "v"(lo), "v"(hi));
    return r;
}
// row permutation: tile mt (0..T-1), row r (0..15) -> feature index
__device__ __forceinline__ int permrow(int mt, int r) {
    return ((mt >> 1) << 5) + ((r >> 2) << 3) + ((mt & 1) << 2) + (r & 3);
}
// R5's exact activation chain on a 4-elem accumulator group -> 2 packed bf16x2
__device__ __forceinline__ void act4(const f32x4 ai, const f32x4 ac, const f32x4 ao,
                                     const f32x4 wc, uint32_t& p0, uint32_t& p1) {
    float hv[4];
    #pragma unroll
    for (int i = 0; i < 4; ++i) {
        float Ei = __builtin_amdgcn_exp2f(ai[i]);                   // e^{-a_i}
        float Ec = __builtin_amdgcn_exp2f(ac[i]);                   // e^{2 a_c}
        float R1 = __builtin_amdgcn_rcpf((1.0f + Ei) * (1.0f + Ec));
        float cp = (Ec - 1.0f) * R1 * TWO_L;                        // 2L*c
        float Eo = __builtin_amdgcn_exp2f(fmaf(wc[i], cp, ao[i]));  // e^{-a_o'}
        float E2 = __builtin_amdgcn_exp2f(cp);                      // e^{2c}
        float R2 = __builtin_amdgcn_rcpf((1.0f + Eo) * (E2 + 1.0f));
        hv[i] = fmaxf((E2 - 1.0f) * R2, 0.0f);                      // relu(O*tanh(c))
    }
    p0 = cvt_pk(hv[0], hv[1]);
    p1 = cvt_pk(hv[2], hv[3]);
}

__global__ __launch_bounds__(512, 4) void gclstm_mfma_kernel(
    const float* __restrict__ x,
    const float* __restrict__ W_i, const float* __restrict__ W_c, const float* __restrict__ W_o,
    const float* __restrict__ bc_i, const float* __restrict__ bc_c, const float* __restrict__ bc_o,
    const float* __restrict__ w_co,
    const float* __restrict__ b_i, const float* __restrict__ b_c, const float* __restrict__ b_o,
    const float* __restrict__ M1, const float* __restrict__ bm1,
    const float* __restrict__ M2, const float* __restrict__ bm2,
    const float* __restrict__ M3, const float* __restrict__ bm3,
    float* __restrict__ out, int n)
{
    __shared__ __align__(16) char lds[LDS_BYTES];
    const int tid  = threadIdx.x;
    const int wid  = tid >> 6;
    const int lane = tid & 63;
    const int g    = lane >> 4;     // lane group 0..3
    const int ln   = lane & 15;

    // ---------------- init: build scaled, row-permuted bf16 fragment tables ----
    if (lane < 32) {
        for (int t = wid; t < 24; t += WAVES) {
            const int gi = t >> 3, mt = t & 7;
            const float* Wg = (gi == 0) ? W_i : (gi == 1) ? W_c : W_o;
            const float sc  = (gi == 1) ? TWO_L : -LOG2E;
            const int row = permrow(mt, ln);  // permuted hid index
            const int k0  = g * 8;            // input-feature index (g in 0..1)
            bf16x8 v;
            #pragma unroll
            for (int j = 0; j < 8; ++j) v[j] = f2bf(Wg[(k0 + j) * HID + row] * sc);
            *(bf16x8*)(lds + GATE_F + t * 512 + lane * 16) = v;
        }
    }
    // M1^T frags: A[r][k] = M1[k*64 + permrow(mt1, r)]; K(hid) natural order.
    for (int t = wid; t < 16; t += WAVES) {
        const int mt = t >> 2, kt = t & 3;
        const int row = permrow(mt, ln);      // permuted m1 index (mt in 0..3)
        const int k0  = kt * 32 + g * 8;
        bf16x8 v;
        #pragma unroll
        for (int j = 0; j < 8; ++j) v[j] = f2bf(M1[(k0 + j) * MH1 + row]);
        *(bf16x8*)(lds + M1_F + t * 1024 + lane * 16) = v;
    }
    // M2^T frags: A[r][k] = M2[k*32 + (mt2*16+r)]; K(m1) natural; rows natural.
    for (int t = wid; t < 4; t += WAVES) {
        const int mt = t >> 1, kt = t & 1;
        const int row = mt * 16 + ln;
        const int k0  = kt * 32 + g * 8;
        bf16x8 v;
        #pragma unroll
        for (int j = 0; j < 8; ++j) v[j] = f2bf(M2[(k0 + j) * MH2 + row]);
        *(bf16x8*)(lds + M2_F + t * 1024 + lane * 16) = v;
    }
    {
        float* biasS = (float*)(lds + BIAS_O);
        if (tid < HID) {
            const int h = permrow(tid >> 4, tid & 15);    // hid perm, mt in 0..7
            biasS[tid]           = (bc_i[h] + b_i[h]) * (-LOG2E);
            biasS[HID + tid]     = (bc_c[h] + b_c[h]) * TWO_L;
            biasS[2 * HID + tid] = (bc_o[h] + b_o[h]) * (-LOG2E);
            ((float*)(lds + WCO_O))[tid] = -0.5f * w_co[h];
        }
        if (tid < MH1) {
            const int m = permrow(tid >> 4, tid & 15);    // m1 perm, mt in 0..3
            ((float*)(lds + BM1_O))[tid] = bm1[m];
        }
        if (tid < MH2) { ((float*)(lds + M3_O))[tid]  = M3[tid];
                         ((float*)(lds + BM2_O))[tid] = bm2[tid]; }
        if (tid == 0)  ((float*)(lds + BM3_O))[0] = bm3[0];
    }
    __syncthreads();

    const float* biasI = (const float*)(lds + BIAS_O);
    const float* biasC = biasI + HID;
    const float* biasO = biasC + HID;
    const float* wcoS  = (const float*)(lds + WCO_O);
    const float* m3S   = (const float*)(lds + M3_O);
    const float* bm1S  = (const float*)(lds + BM1_O);
    const float* bm2S  = (const float*)(lds + BM2_O);
    const float  bm3v  = ((const float*)(lds + BM3_O))[0];

    // ---- dual tile indices for this wave ----
    const long t0 = (long)blockIdx.x * TILES_PER_BLOCK + wid * 2;
    const long baseA = t0 * 16;
    const long baseB = baseA + 16;

    // x B-frags for both tiles (clamped loads; stores are guarded)
    bf16x8 xfA, xfB;
    #pragma unroll
    for (int j = 0; j < 8; ++j) { xfA[j] = 0; xfB[j] = 0; }
    if (g < 2) {
        long nodeA = baseA + ln; if (nodeA >= n) nodeA = n - 1;
        long nodeB = baseB + ln; if (nodeB >= n) nodeB = n - 1;
        const float* xpA = x + nodeA * IN_F + g * 8;
        const float* xpB = x + nodeB * IN_F + g * 8;
        float4 a0 = *(const float4*)xpA, a1 = *(const float4*)(xpA + 4);
        float4 b0 = *(const float4*)xpB, b1 = *(const float4*)(xpB + 4);
        union { uint32_t u[4]; bf16x8 v; } cA, cB;
        cA.u[0] = cvt_pk(a0.x, a0.y); cA.u[1] = cvt_pk(a0.z, a0.w);
        cA.u[2] = cvt_pk(a1.x, a1.y); cA.u[3] = cvt_pk(a1.z, a1.w);
        cB.u[0] = cvt_pk(b0.x, b0.y); cB.u[1] = cvt_pk(b0.z, b0.w);
        cB.u[2] = cvt_pk(b1.x, b1.y); cB.u[3] = cvt_pk(b1.z, b1.w);
        xfA = cA.v; xfB = cB.v;
    }

    // ---- gates + activations; LDS reads SHARED across both tiles ----
    uint32_t hpkA[16], hpkB[16];
    #pragma unroll
    for (int mt = 0; mt < 8; ++mt) {
        const int h0 = mt * 16 + g * 4;             // permuted-bias position
        bf16x8 fi = *(const bf16x8*)(lds + GATE_F + (0 * 8 + mt) * 512 + (lane & 31) * 16);
        bf16x8 fc = *(const bf16x8*)(lds + GATE_F + (1 * 8 + mt) * 512 + (lane & 31) * 16);
        bf16x8 fo = *(const bf16x8*)(lds + GATE_F + (2 * 8 + mt) * 512 + (lane & 31) * 16);
        f32x4 bI = *(const f32x4*)(biasI + h0);
        f32x4 bC = *(const f32x4*)(biasC + h0);
        f32x4 bO = *(const f32x4*)(biasO + h0);
        f32x4 wc = *(const f32x4*)(wcoS + h0);      // -w_co/2

        // tile A MFMAs, tile B MFMAs (frags+biases reused), then activations
        f32x4 aiA = __builtin_amdgcn_mfma_f32_16x16x32_bf16(fi, xfA, bI, 0, 0, 0);
        f32x4 acA = __builtin_amdgcn_mfma_f32_16x16x32_bf16(fc, xfA, bC, 0, 0, 0);
        f32x4 aoA = __builtin_amdgcn_mfma_f32_16x16x32_bf16(fo, xfA, bO, 0, 0, 0);
        f32x4 aiB = __builtin_amdgcn_mfma_f32_16x16x32_bf16(fi, xfB, bI, 0, 0, 0);
        f32x4 acB = __builtin_amdgcn_mfma_f32_16x16x32_bf16(fc, xfB, bC, 0, 0, 0);
        f32x4 aoB = __builtin_amdgcn_mfma_f32_16x16x32_bf16(fo, xfB, bO, 0, 0, 0);

        act4(aiA, acA, aoA, wc, hpkA[mt * 2], hpkA[mt * 2 + 1]);
        act4(aiB, acB, aoB, wc, hpkB[mt * 2], hpkB[mt * 2 + 1]);
    }

    // ---- MLP1: shared M1 frag reads feed both tiles ----
    uint32_t mpkA[8], mpkB[8];
    #pragma unroll
    for (int mt = 0; mt < 4; ++mt) {
        const int r0 = mt * 16 + g * 4;             // permuted-bias position
        f32x4 binit = *(const f32x4*)(bm1S + r0);
        f32x4 accA = binit, accB = binit;
        #pragma unroll
        for (int kt = 0; kt < 4; ++kt) {
            bf16x8 frag = *(const bf16x8*)(lds + M1_F + (mt * 4 + kt) * 1024 + lane * 16);
            union { uint32_t u[4]; bf16x8 v; } bA, bB;
            bA.u[0] = hpkA[4 * kt + 0]; bA.u[1] = hpkA[4 * kt + 1];
            bA.u[2] = hpkA[4 * kt + 2]; bA.u[3] = hpkA[4 * kt + 3];
            bB.u[0] = hpkB[4 * kt + 0]; bB.u[1] = hpkB[4 * kt + 1];
            bB.u[2] = hpkB[4 * kt + 2]; bB.u[3] = hpkB[4 * kt + 3];
            accA = __builtin_amdgcn_mfma_f32_16x16x32_bf16(frag, bA.v, accA, 0, 0, 0);
            accB = __builtin_amdgcn_mfma_f32_16x16x32_bf16(frag, bB.v, accB, 0, 0, 0);
        }
        mpkA[mt * 2]     = cvt_pk(fmaxf(accA[0], 0.f), fmaxf(accA[1], 0.f));
        mpkA[mt * 2 + 1] = cvt_pk(fmaxf(accA[2], 0.f), fmaxf(accA[3], 0.f));
        mpkB[mt * 2]     = cvt_pk(fmaxf(accB[0], 0.f), fmaxf(accB[1], 0.f));
        mpkB[mt * 2 + 1] = cvt_pk(fmaxf(accB[2], 0.f), fmaxf(accB[3], 0.f));
    }

    // ---- MLP2 [32x64] + MLP3 dot; shared M2/w3/bm2 reads ----
    float outA = 0.f, outB = 0.f;
    #pragma unroll
    for (int mt = 0; mt < 2; ++mt) {
        const int r0 = mt * 16 + g * 4;             // m2 index (natural)
        f32x4 binit = *(const f32x4*)(bm2S + r0);
        f32x4 accA = binit, accB = binit;
        #pragma unroll
        for (int kt = 0; kt < 2; ++kt) {
            bf16x8 frag = *(const bf16x8*)(lds + M2_F + (mt * 2 + kt) * 1024 + lane * 16);
            union { uint32_t u[4]; bf16x8 v; } bA, bB;
            bA.u[0] = mpkA[4 * kt + 0]; bA.u[1] = mpkA[4 * kt + 1];
            bA.u[2] = mpkA[4 * kt + 2]; bA.u[3] = mpkA[4 * kt + 3];
            bB.u[0] = mpkB[4 * kt + 0]; bB.u[1] = mpkB[4 * kt + 1];
            bB.u[2] = mpkB[4 * kt + 2]; bB.u[3] = mpkB[4 * kt + 3];
            accA = __builtin_amdgcn_mfma_f32_16x16x32_bf16(frag, bA.v, accA, 0, 0, 0);
            accB = __builtin_amdgcn_mfma_f32_16x16x32_bf16(frag, bB.v, accB, 0, 0, 0);
        }
        f32x4 w3 = *(const f32x4*)(m3S + r0);
        #pragma unroll
        for (int i = 0; i < 4; ++i) {
            outA = fmaf(fmaxf(accA[i], 0.f), w3[i], outA);
            outB = fmaf(fmaxf(accB[i], 0.f), w3[i], outB);
        }
    }
    outA += __shfl_xor(outA, 16); outA += __shfl_xor(outA, 32);
    outB += __shfl_xor(outB, 16); outB += __shfl_xor(outB, 32);
    if (lane < 16) {
        if (baseA + lane < n) out[baseA + lane] = outA + bm3v;
        if (baseB + lane < n) out[baseB + lane] = outB + bm3v;
    }
}

extern "C" void kernel_launch(void* const* d_in, const int* in_sizes, int n_in,
                              void* d_out, int out_size, void* d_ws, size_t ws_size,
                              hipStream_t stream) {
    const float* x    = (const float*)d_in[0];
    // d_in[1] edge_index, d_in[2] edge_weight: dead (ChebConv K=1 on H=0)
    const float* W_i  = (const float*)d_in[3];
    // d_in[4] W_f: dead (multiplies C=0)
    const float* W_c  = (const float*)d_in[5];
    const float* W_o  = (const float*)d_in[6];
    // d_in[7..10] Uc_*: dead (H=0)
    const float* bc_i = (const float*)d_in[11];
    const float* bc_c = (const float*)d_in[13];
    const float* bc_o = (const float*)d_in[14];
    const float* w_co = (const float*)d_in[17];
    const float* b_i  = (const float*)d_in[18];
    const float* b_c  = (const float*)d_in[20];
    const float* b_o  = (const float*)d_in[21];
    const float* M1   = (const float*)d_in[22];
    const float* bm1  = (const float*)d_in[23];
    const float* M2   = (const float*)d_in[24];
    const float* bm2  = (const float*)d_in[25];
    const float* M3   = (const float*)d_in[26];
    const float* bm3  = (const float*)d_in[27];
    float* out = (float*)d_out;

    const int n = in_sizes[0] / IN_F;                   // 500000
    const int tiles = (n + 15) / 16;                    // 31250
    const int grid = (tiles + TILES_PER_BLOCK - 1) / TILES_PER_BLOCK;  // 1954

    gclstm_mfma_kernel<<<grid, 512, 0, stream>>>(
        x, W_i, W_c, W_o, bc_i, bc_c, bc_o, w_co,
        b_i, b_c, b_o, M1, bm1, M2, bm2, M3, bm3, out, n);
}